// Round 1
// baseline (321.817 us; speedup 1.0000x reference)
//
#include <hip/hip_runtime.h>

// MMD loss: source(4096x256 f32), target(4096x256 f32) -> scalar f32.
// Strategy:
//   P1: per-row squared norms (fp32), bf16 cast of concat(total), S1 = sum sq (atomic)
//   P2: column sums s[d] (for ||s||^2)
//   P3: bandwidth = (2N*S1 - 2||s||^2)/(N^2-N)/4 ; store 1/bw
//   M : upper-triangular 128x128 tiles of T*T^T via mfma_f32_16x16x32_bf16,
//       fused 5-exp epilogue, signed weighted sum -> atomicAdd
//   F : out = acc / b^2
#define N_TOT 8192
#define NB    4096
#define DDIM  256

typedef __bf16 bf16x8 __attribute__((ext_vector_type(8)));
typedef float  f32x4  __attribute__((ext_vector_type(4)));

__device__ inline unsigned short f2bf_rne(float x) {
    unsigned int u = __float_as_uint(x);
    unsigned int r = (u + 0x7fffu + ((u >> 16) & 1u)) >> 16;
    return (unsigned short)r;
}

// ws layout (floats): [0]=S1, [1]=signed acc, [2]=inv_bandwidth,
// [64..319]=svec[256], [512..8703]=sq[8192], byte 34816..: bf16 total (4MB)

__global__ void prep_rows(const float* __restrict__ src, const float* __restrict__ tgt,
                          float* __restrict__ wsf, float* __restrict__ sq,
                          unsigned short* __restrict__ totb) {
    int wid  = threadIdx.x >> 6;
    int lane = threadIdx.x & 63;
    int row  = blockIdx.x * 4 + wid;
    const float* rp = (row < NB) ? (src + (size_t)row * DDIM)
                                 : (tgt + (size_t)(row - NB) * DDIM);
    float4 v = ((const float4*)rp)[lane];
    ushort4 o;
    o.x = f2bf_rne(v.x); o.y = f2bf_rne(v.y);
    o.z = f2bf_rne(v.z); o.w = f2bf_rne(v.w);
    ((ushort4*)(totb + (size_t)row * DDIM))[lane] = o;
    float s = v.x*v.x + v.y*v.y + v.z*v.z + v.w*v.w;
    #pragma unroll
    for (int off = 32; off > 0; off >>= 1) s += __shfl_down(s, off);
    if (lane == 0) { sq[row] = s; atomicAdd(&wsf[0], s); }
}

__global__ void col_sums(const float* __restrict__ src, const float* __restrict__ tgt,
                         float* __restrict__ wsf) {
    int d  = threadIdx.x;
    int r0 = blockIdx.x * 256;
    float local = 0.f;
    for (int r = 0; r < 256; ++r) {
        int row = r0 + r;
        const float* rp = (row < NB) ? (src + (size_t)row * DDIM)
                                     : (tgt + (size_t)(row - NB) * DDIM);
        local += rp[d];
    }
    atomicAdd(&wsf[64 + d], local);
}

__global__ void finalize_bw(float* __restrict__ wsf) {
    __shared__ float red[4];
    int t = threadIdx.x;
    float sd = wsf[64 + t];
    float v = sd * sd;
    #pragma unroll
    for (int off = 32; off > 0; off >>= 1) v += __shfl_down(v, off);
    if ((t & 63) == 0) red[t >> 6] = v;
    __syncthreads();
    if (t == 0) {
        float sdot = red[0] + red[1] + red[2] + red[3];
        float S1 = wsf[0];
        float bw_sum = 2.0f * (float)N_TOT * S1 - 2.0f * sdot;
        double denom = (double)N_TOT * (double)N_TOT - (double)N_TOT;
        float bandwidth = (float)((double)bw_sum / denom) * 0.25f;
        wsf[2] = 1.0f / bandwidth;
    }
}

__global__ __launch_bounds__(256) void mmd_tiles(const unsigned short* __restrict__ totb,
                                                 const float* __restrict__ sq,
                                                 float* __restrict__ wsf) {
    int ti = blockIdx.x, tj = blockIdx.y;
    if (tj < ti) return;                       // symmetric: upper triangle only
    int wid  = threadIdx.x >> 6;
    int lane = threadIdx.x & 63;
    int rl = lane & 15, q = lane >> 4;
    int bi = ti * 128 + (wid >> 1) * 64;       // wave covers 64x64
    int bj = tj * 128 + (wid & 1) * 64;

    f32x4 acc[4][4];
    #pragma unroll
    for (int m = 0; m < 4; ++m)
        #pragma unroll
        for (int n = 0; n < 4; ++n) acc[m][n] = (f32x4){0.f, 0.f, 0.f, 0.f};

    size_t baseA[4], baseB[4];
    #pragma unroll
    for (int m = 0; m < 4; ++m) baseA[m] = (size_t)(bi + m*16 + rl) * DDIM + q*8;
    #pragma unroll
    for (int n = 0; n < 4; ++n) baseB[n] = (size_t)(bj + n*16 + rl) * DDIM + q*8;

    #pragma unroll
    for (int k0 = 0; k0 < DDIM; k0 += 32) {
        bf16x8 av[4], bv[4];
        #pragma unroll
        for (int m = 0; m < 4; ++m)
            av[m] = *(const bf16x8*)(totb + baseA[m] + k0);
        #pragma unroll
        for (int n = 0; n < 4; ++n)
            bv[n] = *(const bf16x8*)(totb + baseB[n] + k0);
        #pragma unroll
        for (int m = 0; m < 4; ++m)
            #pragma unroll
            for (int n = 0; n < 4; ++n)
                acc[m][n] = __builtin_amdgcn_mfma_f32_16x16x32_bf16(av[m], bv[n], acc[m][n], 0, 0, 0);
    }

    float inv_bw = wsf[2];
    float local = 0.f;
    #pragma unroll
    for (int m = 0; m < 4; ++m) {
        f32x4 sqi = *(const f32x4*)(sq + bi + m*16 + q*4);   // row = q*4 + e
        #pragma unroll
        for (int n = 0; n < 4; ++n) {
            float sqj = sq[bj + n*16 + rl];                  // col = lane&15
            #pragma unroll
            for (int e = 0; e < 4; ++e) {
                float l2 = fmaxf(sqi[e] + sqj - 2.0f * acc[m][n][e], 0.0f);
                float u = l2 * inv_bw;
                local += __expf(-u) + __expf(-0.5f*u) + __expf(-0.25f*u)
                       + __expf(-0.125f*u) + __expf(-0.0625f*u);
            }
        }
    }
    float scale = (((ti < 32) == (tj < 32)) ? 1.0f : -1.0f) * ((ti == tj) ? 1.0f : 2.0f);
    local *= scale;
    #pragma unroll
    for (int off = 32; off > 0; off >>= 1) local += __shfl_down(local, off);
    if (lane == 0) atomicAdd(&wsf[1], local);
}

__global__ void write_out(const float* __restrict__ wsf, float* __restrict__ out) {
    out[0] = wsf[1] * (1.0f / ((float)NB * (float)NB));
}

extern "C" void kernel_launch(void* const* d_in, const int* in_sizes, int n_in,
                              void* d_out, int out_size, void* d_ws, size_t ws_size,
                              hipStream_t stream) {
    const float* src = (const float*)d_in[0];
    const float* tgt = (const float*)d_in[1];
    float* wsf = (float*)d_ws;
    float* sq  = wsf + 512;
    unsigned short* totb = (unsigned short*)((char*)d_ws + 34816);

    hipMemsetAsync(d_ws, 0, 2048, stream);                     // S1, acc, svec
    prep_rows<<<N_TOT / 4, 256, 0, stream>>>(src, tgt, wsf, sq, totb);
    col_sums<<<32, 256, 0, stream>>>(src, tgt, wsf);
    finalize_bw<<<1, 256, 0, stream>>>(wsf);
    mmd_tiles<<<dim3(64, 64), 256, 0, stream>>>(totb, sq, wsf);
    write_out<<<1, 1, 0, stream>>>(wsf, (float*)d_out);
}

// Round 2
// 117.122 us; speedup vs baseline: 2.7477x; 2.7477x over previous
//
#include <hip/hip_runtime.h>

// MMD loss: source(4096x256 f32), target(4096x256 f32) -> scalar f32.
//   P1 prep_rows : fp32 row norms sq[8192] + bf16 cast of concat (no atomics)
//   P2 col_sums  : column sums svec[256] (atomics spread over 256 addresses)
//   P3 finalize  : S1=sum(sq), sdot=||svec||^2 -> inv_bandwidth (1 block)
//   M  mmd_tiles : triangular 128x128 tiles of T*T^T, m97-style LDS staging
//                  (global_load_lds w=16 + ds_read_b128), mfma 16x16x32 bf16,
//                  1-exp epilogue (e, e^2, e^4, e^8, e^16), per-block partial
//   F  write_out : sum partials, scale by 1/b^2
#define N_TOT 8192
#define NB    4096
#define DDIM  256
#define NTILE 64
#define NBLK  (NTILE * (NTILE + 1) / 2)   // 2080

typedef __bf16 bf16x8 __attribute__((ext_vector_type(8)));
typedef float  f32x4  __attribute__((ext_vector_type(4)));

__device__ inline unsigned short f2bf_rne(float x) {
    unsigned int u = __float_as_uint(x);
    unsigned int r = (u + 0x7fffu + ((u >> 16) & 1u)) >> 16;
    return (unsigned short)r;
}

__device__ inline void gl2lds16(const unsigned short* g, unsigned short* l) {
    __builtin_amdgcn_global_load_lds(
        (const __attribute__((address_space(1))) unsigned int*)g,
        (__attribute__((address_space(3))) unsigned int*)l, 16, 0, 0);
}

// ws layout (floats): [2]=inv_bw, [64..319]=svec, [512..8703]=sq[8192],
// [16384..18463]=part[2080]; byte 131072..: bf16 total (4 MB)

__global__ void prep_rows(const float* __restrict__ src, const float* __restrict__ tgt,
                          float* __restrict__ sq, unsigned short* __restrict__ totb) {
    int wid  = threadIdx.x >> 6;
    int lane = threadIdx.x & 63;
    int row  = blockIdx.x * 4 + wid;
    const float* rp = (row < NB) ? (src + (size_t)row * DDIM)
                                 : (tgt + (size_t)(row - NB) * DDIM);
    float4 v = ((const float4*)rp)[lane];
    ushort4 o;
    o.x = f2bf_rne(v.x); o.y = f2bf_rne(v.y);
    o.z = f2bf_rne(v.z); o.w = f2bf_rne(v.w);
    ((ushort4*)(totb + (size_t)row * DDIM))[lane] = o;
    float s = v.x*v.x + v.y*v.y + v.z*v.z + v.w*v.w;
    #pragma unroll
    for (int off = 32; off > 0; off >>= 1) s += __shfl_down(s, off);
    if (lane == 0) sq[row] = s;
}

__global__ void col_sums(const float* __restrict__ src, const float* __restrict__ tgt,
                         float* __restrict__ wsf) {
    int d  = threadIdx.x;
    int r0 = blockIdx.x * 32;
    float local = 0.f;
    for (int r = 0; r < 32; ++r) {
        int row = r0 + r;
        const float* rp = (row < NB) ? (src + (size_t)row * DDIM)
                                     : (tgt + (size_t)(row - NB) * DDIM);
        local += rp[d];
    }
    atomicAdd(&wsf[64 + d], local);
}

__global__ void finalize_bw(float* __restrict__ wsf, const float* __restrict__ sq) {
    __shared__ float redA[4], redB[4];
    int t = threadIdx.x, lane = t & 63, w = t >> 6;
    float s1 = 0.f;
    for (int i = t; i < N_TOT; i += 256) s1 += sq[i];
    float sd = wsf[64 + t];
    float v2 = sd * sd;
    #pragma unroll
    for (int off = 32; off > 0; off >>= 1) {
        s1 += __shfl_down(s1, off);
        v2 += __shfl_down(v2, off);
    }
    if (lane == 0) { redA[w] = s1; redB[w] = v2; }
    __syncthreads();
    if (t == 0) {
        float S1   = redA[0] + redA[1] + redA[2] + redA[3];
        float sdot = redB[0] + redB[1] + redB[2] + redB[3];
        float bw_sum = 2.0f * (float)N_TOT * S1 - 2.0f * sdot;
        double denom = (double)N_TOT * (double)N_TOT - (double)N_TOT;
        float bandwidth = (float)((double)bw_sum / denom) * 0.25f;
        wsf[2] = 1.0f / bandwidth;
    }
}

__global__ __launch_bounds__(256) void mmd_tiles(const unsigned short* __restrict__ totb,
                                                 const float* __restrict__ sq,
                                                 const float* __restrict__ wsf,
                                                 float* __restrict__ part) {
    __shared__ unsigned short lds_a[128 * 32];
    __shared__ unsigned short lds_b[128 * 32];

    // decode upper-triangular (ti, tj) from 1-D block index
    int idx = blockIdx.x;
    int ti = (int)((129.0f - sqrtf(16641.0f - 8.0f * (float)idx)) * 0.5f);
    if (ti > 63) ti = 63;
    if (ti < 0)  ti = 0;
    while ((ti * (129 - ti)) / 2 > idx) --ti;
    while (((ti + 1) * (128 - ti)) / 2 <= idx) ++ti;
    int tj = ti + idx - (ti * (129 - ti)) / 2;

    int t = threadIdx.x;
    int wid = t >> 6, lane = t & 63;
    int rl = lane & 15, q = lane >> 4;
    int gi0 = ti * 128, gj0 = tj * 128;
    int ia = (wid >> 1) * 64, jb = (wid & 1) * 64;

    // staging: chunk c in [0,512): row=c>>2, koff=(c&3)*8; thread owns c=t, c=t+256
    const unsigned short* gA0 = totb + (size_t)(gi0 + (t >> 2)) * DDIM + (t & 3) * 8;
    const unsigned short* gA1 = gA0 + (size_t)64 * DDIM;
    const unsigned short* gB0 = totb + (size_t)(gj0 + (t >> 2)) * DDIM + (t & 3) * 8;
    const unsigned short* gB1 = gB0 + (size_t)64 * DDIM;
    unsigned short* lA0 = &lds_a[t * 8];
    unsigned short* lA1 = &lds_a[(t + 256) * 8];
    unsigned short* lB0 = &lds_b[t * 8];
    unsigned short* lB1 = &lds_b[(t + 256) * 8];

    f32x4 acc[4][4];
    #pragma unroll
    for (int m = 0; m < 4; ++m)
        #pragma unroll
        for (int n = 0; n < 4; ++n) acc[m][n] = (f32x4){0.f, 0.f, 0.f, 0.f};

    for (int k0 = 0; k0 < DDIM; k0 += 32) {
        gl2lds16(gA0 + k0, lA0);
        gl2lds16(gA1 + k0, lA1);
        gl2lds16(gB0 + k0, lB0);
        gl2lds16(gB1 + k0, lB1);
        __syncthreads();
        bf16x8 av[4], bv[4];
        #pragma unroll
        for (int m = 0; m < 4; ++m)
            av[m] = *(const bf16x8*)&lds_a[(ia + m * 16 + rl) * 32 + q * 8];
        #pragma unroll
        for (int n = 0; n < 4; ++n)
            bv[n] = *(const bf16x8*)&lds_b[(jb + n * 16 + rl) * 32 + q * 8];
        #pragma unroll
        for (int m = 0; m < 4; ++m)
            #pragma unroll
            for (int n = 0; n < 4; ++n)
                acc[m][n] = __builtin_amdgcn_mfma_f32_16x16x32_bf16(av[m], bv[n], acc[m][n], 0, 0, 0);
        __syncthreads();
    }

    // epilogue: 1 exp + 4 squarings (bandwidth ladder is powers of 2)
    float inv_bw16 = wsf[2] * 0.0625f;
    float local = 0.f;
    #pragma unroll
    for (int m = 0; m < 4; ++m) {
        f32x4 sqi = *(const f32x4*)(sq + gi0 + ia + m * 16 + q * 4);
        #pragma unroll
        for (int n = 0; n < 4; ++n) {
            float sqj = sq[gj0 + jb + n * 16 + rl];
            #pragma unroll
            for (int e = 0; e < 4; ++e) {
                float l2 = fmaxf(sqi[e] + sqj - 2.0f * acc[m][n][e], 0.0f);
                float e1 = __expf(-l2 * inv_bw16);
                float e2 = e1 * e1, e4 = e2 * e2, e8 = e4 * e4;
                local += e1 + e2 + e4 + e8 + e8 * e8;
            }
        }
    }
    #pragma unroll
    for (int off = 32; off > 0; off >>= 1) local += __shfl_down(local, off);
    float* red = (float*)lds_a;
    if (lane == 0) red[wid] = local;
    __syncthreads();
    if (t == 0) {
        float tot = red[0] + red[1] + red[2] + red[3];
        float scale = (((ti < 32) == (tj < 32)) ? 1.0f : -1.0f) * ((ti == tj) ? 1.0f : 2.0f);
        part[idx] = tot * scale;
    }
}

__global__ void write_out(const float* __restrict__ part, float* __restrict__ out) {
    __shared__ float red[4];
    int t = threadIdx.x, lane = t & 63, w = t >> 6;
    float s = 0.f;
    for (int i = t; i < NBLK; i += 256) s += part[i];
    #pragma unroll
    for (int off = 32; off > 0; off >>= 1) s += __shfl_down(s, off);
    if (lane == 0) red[w] = s;
    __syncthreads();
    if (t == 0)
        out[0] = (red[0] + red[1] + red[2] + red[3]) * (1.0f / ((float)NB * (float)NB));
}

extern "C" void kernel_launch(void* const* d_in, const int* in_sizes, int n_in,
                              void* d_out, int out_size, void* d_ws, size_t ws_size,
                              hipStream_t stream) {
    const float* src = (const float*)d_in[0];
    const float* tgt = (const float*)d_in[1];
    float* wsf  = (float*)d_ws;
    float* sq   = wsf + 512;
    float* part = wsf + 16384;
    unsigned short* totb = (unsigned short*)((char*)d_ws + 131072);

    hipMemsetAsync(d_ws, 0, 2048, stream);                       // svec + scalars
    prep_rows<<<N_TOT / 4, 256, 0, stream>>>(src, tgt, sq, totb);
    col_sums<<<256, 256, 0, stream>>>(src, tgt, wsf);
    finalize_bw<<<1, 256, 0, stream>>>(wsf, sq);
    mmd_tiles<<<NBLK, 256, 0, stream>>>(totb, sq, wsf, part);
    write_out<<<1, 256, 0, stream>>>(part, (float*)d_out);
}